// Round 8
// baseline (858.051 us; speedup 1.0000x reference)
//
#include <hip/hip_runtime.h>
#include <float.h>

// VectorQuantize: h=8 heads, c=2048 codes, d=64, b=8, t=2048 (n=16384 vec/head)
#define H   8
#define C   2048
#define D   64
#define NPH 16384     // vectors per head (b*t)
#define HD  512       // h*d
#define DECAYF 0.9f
#define CT  128       // code tile
#define NT  (C/CT)    // 16 code tiles
#define KCH 16        // k-chunk (4 phases per tile)

// ---------------------------------------------------------------------------
// Kernel 0: e_sq[h,c] = sum_d ke[h,c,d]^2
// ---------------------------------------------------------------------------
__global__ __launch_bounds__(256) void vq_esq_kernel(const float* __restrict__ ke,
                                                     float* __restrict__ esq) {
    int i = blockIdx.x * 256 + threadIdx.x;   // 0 .. H*C-1
    const float* e = ke + (size_t)i * D;
    float s = 0.f;
#pragma unroll
    for (int d = 0; d < D; ++d) s = fmaf(e[d], e[d], s);
    esq[i] = s;
}

// ---------------------------------------------------------------------------
// Kernel 1: register-tiled distance GEMM + argmin.
//   R8 vs R7: occupancy 2->3 blocks/CU. R7 had spill-free 88 VGPR but
//   VALUBusy 32% at 2 waves/SIMD: ds_read latency unhidden (LDS-pipe demand
//   ratio 1.5x caps VALU at 67%; TLP too low to reach the cap). Shrink LDS:
//   k-chunks of 16 (8KB ping-pong bufs), esq read from global in epilogue
//   (sesqa dropped). LDS ~49.7KB -> 3 blocks/CU, 64 barriers (loads stay a
//   full phase ahead; nothing exposed between barriers).
//   Thread (tx,ty)=(tid&15,tid>>4): vecs ty*8..+7, codes {tx*4..+3} u
//   {64+tx*4..+3} per 128-tile (16B lane stride -> 2-way wrap = free).
//   Score = esq[c] - 2*dot (x^2 row-constant dropped; R7 passed, absmax
//   0.0156). fmaf k ascending, first-min ascending-index tie-break.
// ---------------------------------------------------------------------------
// smem float offsets:
//   sx    [    0,  8192)  x^T [k][v] 64x128   (alive until scatter)
//   se0   [ 8192, 10240)  chunk buf A [kk][c] 16x128
//   se1   [10240, 12288)  chunk buf B [kk][c] 16x128
//   sidx  [12288, 12416)  chosen code per vector (int, 128)
//   rb = smem+8192 [16][128] (alias se0), ri = (int*)(smem+10240) (alias se1)
#define SMEM_FLOATS 12416

__global__ __launch_bounds__(256, 2)
void vq_main_kernel(const float* __restrict__ x,
                    const float* __restrict__ ke,
                    const float* __restrict__ esq,
                    float* __restrict__ outq,
                    float* __restrict__ outi,
                    float* __restrict__ embsum) {
    __shared__ __align__(16) float smem[SMEM_FLOATS];
    float* sx   = smem;
    float* se0  = smem + 8192;
    float* se1  = smem + 10240;
    int*   sidx = (int*)(smem + 12288);

    const int tid = threadIdx.x;
    const int tx  = tid & 15;    // code group
    const int ty  = tid >> 4;    // vec group (8 vecs)
    const int h   = blockIdx.x & 7;
    const int vt  = blockIdx.x >> 3;
    const int n0  = vt * 128;    // first vector of this block (within head)

    const float* keh  = ke  + (size_t)h * C * D;
    const float* esqh = esq + (size_t)h * C;

    // staging role: code col pr, k-offset pk within chunk (8 floats/thread)
    const int pr = tid >> 1;
    const int pk = (tid & 1) * 8;

    float4 pf[2];
    // issue phase-0 loads (tile0, kc0) first: latency hides under x staging
    {
        const float* ep = keh + (size_t)pr * D + pk;
        pf[0] = ((const float4*)ep)[0];
        pf[1] = ((const float4*)ep)[1];
    }

    // ---- stage x^T: sx[k][v] = x[n0+v][h*64+k] ----
    {
        const int v  = tid >> 1;
        const int kb = (tid & 1) * 32;
        const float* xp = x + (size_t)(n0 + v) * HD + (size_t)h * D + kb;
#pragma unroll
        for (int i = 0; i < 8; ++i) {
            float4 w = ((const float4*)xp)[i];
            sx[(kb + 4 * i + 0) * 128 + v] = w.x;
            sx[(kb + 4 * i + 1) * 128 + v] = w.y;
            sx[(kb + 4 * i + 2) * 128 + v] = w.z;
            sx[(kb + 4 * i + 3) * 128 + v] = w.w;
        }
    }

    // write phase 0 -> se0 ; issue phase 1 loads -> pf
#pragma unroll
    for (int i = 0; i < 2; ++i) {
        se0[(pk + 4 * i + 0) * 128 + pr] = pf[i].x;
        se0[(pk + 4 * i + 1) * 128 + pr] = pf[i].y;
        se0[(pk + 4 * i + 2) * 128 + pr] = pf[i].z;
        se0[(pk + 4 * i + 3) * 128 + pr] = pf[i].w;
    }
    {
        const float* ep = keh + (size_t)pr * D + KCH + pk;
        pf[0] = ((const float4*)ep)[0];
        pf[1] = ((const float4*)ep)[1];
    }
    __syncthreads();

    float best[8];
    int   bidx[8];
#pragma unroll
    for (int r = 0; r < 8; ++r) { best[r] = FLT_MAX; bidx[r] = 0x7fffffff; }

#pragma unroll 1
    for (int t = 0; t < NT; ++t) {
        float acc[8][8];
#pragma unroll
        for (int r = 0; r < 8; ++r)
#pragma unroll
            for (int j = 0; j < 8; ++j) acc[r][j] = 0.f;

        // 4 phases per tile; phase kc computes se[kc&1], writes pf->se[(kc+1)&1],
        // issues loads for global phase t*4+kc+2 (wrapped; tail reloads harmless).
#pragma unroll
        for (int kc = 0; kc < 4; ++kc) {
            float* se_cur = (kc & 1) ? se1 : se0;
            float* se_nxt = (kc & 1) ? se0 : se1;

            // write pf (phase kc+1 data) into the other buffer
#pragma unroll
            for (int i = 0; i < 2; ++i) {
                se_nxt[(pk + 4 * i + 0) * 128 + pr] = pf[i].x;
                se_nxt[(pk + 4 * i + 1) * 128 + pr] = pf[i].y;
                se_nxt[(pk + 4 * i + 2) * 128 + pr] = pf[i].z;
                se_nxt[(pk + 4 * i + 3) * 128 + pr] = pf[i].w;
            }
            // issue loads for phase p+2
            {
                const int pl = (t * 4 + kc + 2) & (NT * 4 - 1);
                const int tl = pl >> 2;
                const int kl = pl & 3;
                const float* ep = keh + (size_t)(tl * CT + pr) * D + kl * KCH + pk;
                pf[0] = ((const float4*)ep)[0];
                pf[1] = ((const float4*)ep)[1];
            }

            // compute current chunk: k = kc*16 + kk
#pragma unroll 2
            for (int kk = 0; kk < KCH; ++kk) {
                const int k = kc * KCH + kk;
                float4 xa0 = *(const float4*)&sx[k * 128 + ty * 8];
                float4 xa1 = *(const float4*)&sx[k * 128 + ty * 8 + 4];
                float4 e0  = *(const float4*)&se_cur[kk * 128 + tx * 4];
                float4 e1  = *(const float4*)&se_cur[kk * 128 + 64 + tx * 4];
                float xa[8] = {xa0.x, xa0.y, xa0.z, xa0.w, xa1.x, xa1.y, xa1.z, xa1.w};
                float eb[8] = {e0.x, e0.y, e0.z, e0.w, e1.x, e1.y, e1.z, e1.w};
#pragma unroll
                for (int r = 0; r < 8; ++r)
#pragma unroll
                    for (int j = 0; j < 8; ++j)
                        acc[r][j] = fmaf(xa[r], eb[j], acc[r][j]);
            }
            __syncthreads();
        }

        // ---- epilogue tile t (register + global only; esq from L1) ----
        {
            float4 q0 = *(const float4*)&esqh[t * CT + tx * 4];
            float4 q1 = *(const float4*)&esqh[t * CT + 64 + tx * 4];
            float eq[8] = {q0.x, q0.y, q0.z, q0.w, q1.x, q1.y, q1.z, q1.w};
#pragma unroll
            for (int r = 0; r < 8; ++r) {
#pragma unroll
                for (int j = 0; j < 8; ++j) {   // ascending code order per thread
                    const int cc = (j < 4) ? (tx * 4 + j) : (64 + tx * 4 + (j - 4));
                    float sc = fmaf(-2.f, acc[r][j], eq[j]);
                    if (sc < best[r]) { best[r] = sc; bidx[r] = t * CT + cc; }
                }
            }
        }
    }

    // ---- cross-thread argmin reduction (rb/ri alias se0/se1) ----
    float* rb = smem + 8192;
    int*   ri = (int*)(smem + 10240);
#pragma unroll
    for (int r = 0; r < 8; ++r) {
        rb[tx * 128 + ty * 8 + r] = best[r];
        ri[tx * 128 + ty * 8 + r] = bidx[r];
    }
    __syncthreads();
    if (tid < 128) {
        const int v = tid;
        float bb = FLT_MAX;
        int   bi = 0x7fffffff;
        for (int g = 0; g < 16; ++g) {
            float b = rb[g * 128 + v];
            int   i = ri[g * 128 + v];
            if (b < bb || (b == bb && i < bi)) { bb = b; bi = i; }
        }
        sidx[v] = bi;
        outi[(size_t)(n0 + v) * H + h] = (float)bi;   // [b,t,h]
    }
    __syncthreads();

    // ---- gather quantized vectors + scatter-add into emb_sum ----
    {
        const int v  = tid >> 1;
        const int db = (tid & 1) * 32;
        const int ci = sidx[v];
        const float* ev = keh + (size_t)ci * D + db;
        float* qo = outq + (size_t)(n0 + v) * HD + (size_t)h * D + db;
#pragma unroll
        for (int i = 0; i < 8; ++i)
            ((float4*)qo)[i] = ((const float4*)ev)[i];

        float* es = embsum + ((size_t)h * C + ci) * D + db;
#pragma unroll
        for (int d = 0; d < 32; ++d)
            atomicAdd(es + d, sx[(db + d) * 128 + v]);
    }
}

// ---------------------------------------------------------------------------
// Kernel 2: new_ke = key_optim ? ke + 0.9*(emb_sum - ke) : ke
// ---------------------------------------------------------------------------
__global__ __launch_bounds__(256) void vq_lerp_kernel(const float* __restrict__ ke,
                                                      const float* __restrict__ embsum,
                                                      const int* __restrict__ ko,
                                                      float* __restrict__ outk) {
    int i = (blockIdx.x * 256 + threadIdx.x) * 4;   // H*C*D = 1048576 floats
    const int on = ko[0];
    float4 k4 = *(const float4*)(ke + i);
    float4 s4 = *(const float4*)(embsum + i);
    float4 o4;
    if (on) {
        o4.x = k4.x + DECAYF * (s4.x - k4.x);
        o4.y = k4.y + DECAYF * (s4.y - k4.y);
        o4.z = k4.z + DECAYF * (s4.z - k4.z);
        o4.w = k4.w + DECAYF * (s4.w - k4.w);
    } else {
        o4 = k4;
    }
    *(float4*)(outk + i) = o4;
}

extern "C" void kernel_launch(void* const* d_in, const int* in_sizes, int n_in,
                              void* d_out, int out_size, void* d_ws, size_t ws_size,
                              hipStream_t stream) {
    const float* x  = (const float*)d_in[0];
    const float* ke = (const float*)d_in[1];
    const int*   ko = (const int*)d_in[2];

    float* out  = (float*)d_out;
    float* outq = out;                                   // 8,388,608 floats
    float* outi = out + (size_t)H * NPH * D;             // +131,072 floats
    float* outk = outi + (size_t)NPH * H;                // +1,048,576 floats

    float* embsum = (float*)d_ws;                        // H*C*D f32
    float* esq    = embsum + (size_t)H * C * D;          // 16,384 f32

    // zero the scatter accumulator every call (graph-replay safe)
    hipMemsetAsync(embsum, 0, (size_t)H * C * D * sizeof(float), stream);

    vq_esq_kernel<<<(H * C) / 256, 256, 0, stream>>>(ke, esq);
    vq_main_kernel<<<1024, 256, 0, stream>>>(x, ke, esq, outq, outi, embsum);
    vq_lerp_kernel<<<(H * C * D) / (256 * 4), 256, 0, stream>>>(ke, embsum, ko, outk);
}